// Round 7
// baseline (1191.817 us; speedup 1.0000x reference)
//
#include <hip/hip_runtime.h>

#define CIN  16
#define COUT 16
#define SNUM 4
#define PPT  4    // points (n) per thread -> ALL global streams 16B/lane
#define TPB  256  // threads per block

typedef float  f32x4 __attribute__((ext_vector_type(4)));  // native clang vec
typedef int    i32x4 __attribute__((ext_vector_type(4)));

// out[b,o,n] = sum_i W[o,i,s(b,n)] * x[b,i,n] + bias[o]
//
// R1: PPT=4 full unroll, no wave cap -> VGPR=256, occ 10% -> 205us
// R3: PPT=2 (8B/lane) -> 3.3x traffic amplification (partial-line RFO) -> 388us
// R6: PPT=4, unroll 4, cap(256,4) -> VGPR=64, occ 38%, bytes 0.41GB, 0 conflicts,
//     but 170us @ 2.4 TB/s with ALL pipes idle -> latency-bound: only 4KB of
//     loads in flight per wave, vmcnt drains between unroll groups.
// R7: preload ALL 16 channel vectors into registers (16KB in flight per wave,
//     progressive vmcnt(15..0) waits -> one exposed latency), cap(256,3).
__global__ __launch_bounds__(TPB, 3) void apr_conv1x1_kernel(
    const float* __restrict__ x,      // [B, CIN, N]
    const float* __restrict__ w,      // [COUT, CIN, SNUM]
    const float* __restrict__ bias,   // [COUT]
    const int*   __restrict__ sidx,   // [B, N]
    float*       __restrict__ out,    // [B, COUT, N]
    int N)
{
    // LDS weights, f32x4 index [i][ko][s]; elem j = W[o=ko*4+j][i][s].
    // Lane-varying address component is only s*16 B -> <=4 distinct
    // addresses/wave -> broadcast-class, conflict-free (R1/R3/R6: 0 conflicts).
    __shared__ f32x4 w4[CIN * 4 * SNUM];   // 256 * 16B = 4 KiB

    const int t = threadIdx.x;
    {
        const int s  = t & 3;
        const int ko = (t >> 2) & 3;
        const int i  = t >> 4;
        f32x4 v;
        v.x = w[((ko * 4 + 0) * CIN + i) * SNUM + s];
        v.y = w[((ko * 4 + 1) * CIN + i) * SNUM + s];
        v.z = w[((ko * 4 + 2) * CIN + i) * SNUM + s];
        v.w = w[((ko * 4 + 3) * CIN + i) * SNUM + s];
        w4[t] = v;
    }

    const unsigned tid  = blockIdx.x * TPB + t;
    const unsigned tpb_ = (unsigned)(N >> 2);         // threads per batch (PPT=4)
    const unsigned b    = (tid >= tpb_) ? 1u : 0u;    // B == 2: compare, no div
    const unsigned n    = (tid - b * tpb_) << 2;      // first of 4 consecutive n

    const float* xb = x   + (size_t)b * CIN  * N + n;
    float*       ob = out + (size_t)b * COUT * N + n;
    const i32x4 sv = *(const i32x4*)(sidx + (size_t)b * N + n);  // 16B/lane

    // ---- MLP phase: issue all 16 channel loads back-to-back (16KB/wave) ----
    f32x4 xv[16];
    #pragma unroll
    for (int i = 0; i < CIN; ++i)
        xv[i] = *(const f32x4*)(xb + (size_t)i * N);   // global_load_dwordx4 x16

    const int sb0 = sv.x, sb1 = sv.y, sb2 = sv.z, sb3 = sv.w;

    float acc[PPT][COUT];
    #pragma unroll
    for (int o = 0; o < COUT; ++o) {
        const float bv = bias[o];   // uniform address -> scalar load
        acc[0][o] = bv; acc[1][o] = bv; acc[2][o] = bv; acc[3][o] = bv;
    }

    __syncthreads();   // w4 ready (placed after load-issue: loads fly over it)

#define FMA4(p, wv, xs)                         \
    acc[p][ko * 4 + 0] += (wv).x * (xs);        \
    acc[p][ko * 4 + 1] += (wv).y * (xs);        \
    acc[p][ko * 4 + 2] += (wv).z * (xs);        \
    acc[p][ko * 4 + 3] += (wv).w * (xs);

    // Consume in load order: compiler emits progressive vmcnt(15..0) waits.
    #pragma unroll
    for (int i = 0; i < CIN; ++i) {
        const f32x4 xc = xv[i];
        #pragma unroll
        for (int ko = 0; ko < 4; ++ko) {
            const int base = i * 16 + ko * 4;
            const f32x4 w0 = w4[base + sb0];   // ds_read_b128 broadcast
            const f32x4 w1 = w4[base + sb1];
            const f32x4 w2 = w4[base + sb2];
            const f32x4 w3 = w4[base + sb3];
            FMA4(0, w0, xc.x)
            FMA4(1, w1, xc.y)
            FMA4(2, w2, xc.z)
            FMA4(3, w3, xc.w)
        }
    }
#undef FMA4

    #pragma unroll
    for (int o = 0; o < COUT; ++o) {
        f32x4 r;
        r.x = acc[0][o]; r.y = acc[1][o]; r.z = acc[2][o]; r.w = acc[3][o];
        // NT: output is never re-read; don't let it evict x from L3.
        __builtin_nontemporal_store(r, (f32x4*)(ob + (size_t)o * N));
    }
}

extern "C" void kernel_launch(void* const* d_in, const int* in_sizes, int n_in,
                              void* d_out, int out_size, void* d_ws, size_t ws_size,
                              hipStream_t stream) {
    const float* x    = (const float*)d_in[0];   // [B, CIN, N]
    const float* w    = (const float*)d_in[1];   // [COUT, CIN, SNUM, 1, 1]
    const float* bias = (const float*)d_in[2];   // [COUT]
    const int*   sidx = (const int*)d_in[3];     // [B, N]
    float* out = (float*)d_out;

    const int B = 2;
    const int N = in_sizes[3] / B;               // 2097152
    const int total_points = B * N;              // 4M, divisible by PPT*TPB
    const int nthreads = total_points / PPT;
    const int nblocks  = (nthreads + TPB - 1) / TPB;

    apr_conv1x1_kernel<<<nblocks, TPB, 0, stream>>>(x, w, bias, sidx, out, N);
}